// Round 6
// baseline (105.138 us; speedup 1.0000x reference)
//
#include <hip/hip_runtime.h>

// Mo3ENet neighbor selection: B=256, PER=1024, NIN=256, NOUT=768, K=32, R=6
// Packed-f32 scan: 2 candidates/lane via v_pk_add/mul_f32; ballot compaction;
// pair-SoA LDS layout; coalesced 4-array epilogue.
// Outputs (concatenated float32):
//   [0) src_ii | [E) tgt | [2E) m_ii | [3E) dist_ii |
//   [4E) src_io | [5E) tgt | [6E) m_io | [7E) dist_io

constexpr int BB    = 256;
constexpr int PERN  = 1024;
constexpr int NINC  = 256;
constexpr int KK    = 32;
constexpr unsigned EE = 256u * 256u * 32u;  // 2097152 elements per array

typedef float v2f __attribute__((ext_vector_type(2)));

__device__ __forceinline__ v2f pk_add(v2f a, v2f b) {
    v2f d; asm("v_pk_add_f32 %0, %1, %2" : "=v"(d) : "v"(a), "v"(b)); return d;
}
__device__ __forceinline__ v2f pk_mul(v2f a, v2f b) {
    v2f d; asm("v_pk_mul_f32 %0, %1, %2" : "=v"(d) : "v"(a), "v"(b)); return d;
}

__device__ __forceinline__ int prefix_lt(unsigned long long m) {
    return __builtin_amdgcn_mbcnt_hi((unsigned)(m >> 32),
           __builtin_amdgcn_mbcnt_lo((unsigned)m, 0u));
}

__global__ __launch_bounds__(1024) void mo3e_kernel(const float* __restrict__ pos,
                                                    float* __restrict__ out) {
    // Pair-SoA: coordinate c of point j lives at sq[c*1024 + fo(j)],
    // fo(j) = ((j>>7)*64 + (j&63))*2 + ((j>>6)&1). Lane l of pair-group p
    // reads points (p*128+l, p*128+64+l) as one float2.
    __shared__ float sq[3 * PERN];       // 12 KB
    __shared__ int   slotbuf[16][64];    // 4 KB

    const int b   = blockIdx.x >> 4;     // 16 blocks per batch
    const int tid = threadIdx.x;
    const int w   = tid >> 6;
    const int l   = tid & 63;
    const int i   = __builtin_amdgcn_readfirstlane((blockIdx.x & 15) * 16 + w);

    // Stage batch positions into pair layout (one point per thread).
    {
        const float* gp = pos + (size_t)b * PERN * 3;
        const int fo = (((tid >> 7) << 6) | (tid & 63)) * 2 + ((tid >> 6) & 1);
        sq[fo]            = gp[tid * 3 + 0];
        sq[PERN + fo]     = gp[tid * 3 + 1];
        sq[2 * PERN + fo] = gp[tid * 3 + 2];
    }
    __syncthreads();

    const int fi = (((i >> 7) << 6) | (i & 63)) * 2 + ((i >> 6) & 1);
    const float xi = sq[fi], yi = sq[PERN + fi], zi = sq[2 * PERN + fi];
    // (q - xi)^2 == (xi - q)^2 bitwise; pre-negate target so scan is pure pk_add.
    const v2f nx = {-xi, -xi}, ny = {-yi, -yi}, nz = {-zi, -zi};

    const v2f* xq = (const v2f*)sq;
    const v2f* yq = (const v2f*)(sq + PERN);
    const v2f* zq = (const v2f*)(sq + 2 * PERN);

    int* slots = slotbuf[w];

    // ================= ii scan: pair-groups 0..1 (j in [0,256)) =================
    int S0ii;
    {
        unsigned long long msk[4];
        int cnt = 0;
#pragma unroll
        for (int p = 0; p < 2; ++p) {
            const v2f qx = xq[p * 64 + l], qy = yq[p * 64 + l], qz = zq[p * 64 + l];
            const v2f dx = pk_add(qx, nx), dy = pk_add(qy, ny), dz = pk_add(qz, nz);
            // exact reference order per half: (dx^2 + dy^2) + dz^2
            const v2f d2 = pk_add(pk_add(pk_mul(dx, dx), pk_mul(dy, dy)), pk_mul(dz, dz));
            const int ja = p * 128 + l, jb = ja + 64;
            const bool va = (d2.x < 36.0f) && (ja != i);
            const bool vb = (d2.y < 36.0f) && (jb != i);
            const unsigned long long ma = __ballot(va);
            {
                const int slot = cnt + prefix_lt(ma);
                if (va && slot < KK) slots[slot] = ja;
                cnt += __popcll(ma);
            }
            const unsigned long long mb = __ballot(vb);
            {
                const int slot = cnt + prefix_lt(mb);
                if (vb && slot < KK) slots[slot] = jb;
                cnt += __popcll(mb);
            }
            msk[2 * p] = ma;
            msk[2 * p + 1] = mb;
        }
        S0ii = cnt < KK ? cnt : KK;
        if (S0ii < KK) {  // pad: smallest invalid indices (incl. j==i)
            int pc = S0ii;
#pragma unroll
            for (int g = 0; g < 4; ++g) {
                const unsigned long long inv = ~msk[g];
                const int slot = pc + prefix_lt(inv);
                if (((inv >> l) & 1ull) && slot < KK) slots[slot] = g * 64 + l;
                pc += __popcll(inv);
                if (pc >= KK) break;  // inv masks are dense: exits after ~1 group
            }
        }
    }

    // ================= io scan: pair-groups 2..7 (c in [256,1024)) =================
    int S0io;
    {
        unsigned long long msk[12];
        int cnt = 0;
#pragma unroll
        for (int p = 2; p < 8; ++p) {
            const v2f qx = xq[p * 64 + l], qy = yq[p * 64 + l], qz = zq[p * 64 + l];
            const v2f dx = pk_add(qx, nx), dy = pk_add(qy, ny), dz = pk_add(qz, nz);
            const v2f d2 = pk_add(pk_add(pk_mul(dx, dx), pk_mul(dy, dy)), pk_mul(dz, dz));
            const int ca = p * 128 + l, cb = ca + 64;
            const bool va = (d2.x < 36.0f);
            const bool vb = (d2.y < 36.0f);
            const unsigned long long ma = __ballot(va);
            {
                const int slot = cnt + prefix_lt(ma);
                if (va && slot < KK) slots[KK + slot] = ca;
                cnt += __popcll(ma);
            }
            const unsigned long long mb = __ballot(vb);
            {
                const int slot = cnt + prefix_lt(mb);
                if (vb && slot < KK) slots[KK + slot] = cb;
                cnt += __popcll(mb);
            }
            msk[2 * (p - 2)] = ma;
            msk[2 * (p - 2) + 1] = mb;
        }
        S0io = cnt < KK ? cnt : KK;
        if (S0io < KK) {
            int pc = S0io;
#pragma unroll
            for (int g = 0; g < 12; ++g) {
                const unsigned long long inv = ~msk[g];
                const int slot = pc + prefix_lt(inv);
                if (((inv >> l) & 1ull) && slot < KK) slots[KK + slot] = NINC + g * 64 + l;
                pc += __popcll(inv);
                if (pc >= KK) break;
            }
        }
    }

    // ================= epilogue: half-wave pull, 4 coalesced stores =================
    {
        const int h = l >> 5;        // 0 = ii row, 1 = io row
        const int k = l & 31;
        const int idx = slots[l];    // candidate index within batch [0,1024)
        const int fg = (((idx >> 7) << 6) | (idx & 63)) * 2 + ((idx >> 6) & 1);
        const float dxe = xi - sq[fg];
        const float dye = yi - sq[PERN + fg];
        const float dze = zi - sq[2 * PERN + fg];
        const float d2e = dxe * dxe + dye * dye + dze * dze;  // dist tol 0.12: any order

        const int S0 = h ? S0io : S0ii;
        const bool mv = k < S0;
        const float dist = mv ? __builtin_amdgcn_sqrtf(d2e) : 0.0f;

        const int goff = b * PERN;
        const unsigned e0  = (unsigned)(b * NINC + i) * KK;
        const unsigned off = (h ? 4u * EE : 0u) + e0 + (unsigned)k;

        out[off]           = (float)(goff + idx);  // src (io idx already incl. +NIN)
        out[off + EE]      = (float)(goff + i);    // tgt
        out[off + 2u * EE] = mv ? 1.0f : 0.0f;     // mask
        out[off + 3u * EE] = dist;                 // dist
    }
}

extern "C" void kernel_launch(void* const* d_in, const int* in_sizes, int n_in,
                              void* d_out, int out_size, void* d_ws, size_t ws_size,
                              hipStream_t stream) {
    const float* pos = (const float*)d_in[0];
    float* out = (float*)d_out;

    // 16 blocks/batch x 256 batches; 1024 threads = 16 waves = 16 targets/block.
    mo3e_kernel<<<dim3(BB * 16), dim3(1024), 0, stream>>>(pos, out);
}

// Round 7
// 102.289 us; speedup vs baseline: 1.0278x; 1.0278x over previous
//
#include <hip/hip_runtime.h>

// Mo3ENet neighbor selection: B=256, PER=1024, NIN=256, NOUT=768, K=32, R=6
// Round 7: software-pipelined coord loads -> all d2 in regs -> batched ballots
// -> branch-free compaction. Pair-SoA LDS layout, pk-f32 math, coalesced epilogue.
// Outputs (concatenated float32):
//   [0) src_ii | [E) tgt | [2E) m_ii | [3E) dist_ii |
//   [4E) src_io | [5E) tgt | [6E) m_io | [7E) dist_io

constexpr int BB    = 256;
constexpr int PERN  = 1024;
constexpr int KK    = 32;
constexpr unsigned EE = 256u * 256u * 32u;  // 2097152 elements per array

typedef float v2f __attribute__((ext_vector_type(2)));

__device__ __forceinline__ v2f pk_add(v2f a, v2f b) {
    v2f d; asm("v_pk_add_f32 %0, %1, %2" : "=v"(d) : "v"(a), "v"(b)); return d;
}
__device__ __forceinline__ v2f pk_mul(v2f a, v2f b) {
    v2f d; asm("v_pk_mul_f32 %0, %1, %2" : "=v"(d) : "v"(a), "v"(b)); return d;
}

__device__ __forceinline__ int prefix_lt(unsigned long long m) {
    return __builtin_amdgcn_mbcnt_hi((unsigned)(m >> 32),
           __builtin_amdgcn_mbcnt_lo((unsigned)m, 0u));
}

__global__ __launch_bounds__(1024) void mo3e_kernel(const float* __restrict__ pos,
                                                    float* __restrict__ out) {
    // Pair-SoA: coord c of point j at sq[c*1024 + fo(j)],
    // fo(j) = ((j>>7)*64 + (j&63))*2 + ((j>>6)&1). Lane l of pair-group p
    // reads points (p*128+l, p*128+64+l) as one float2.
    // Linear 64-candidate group g (cands g*64+l) maps to pair p=g>>1, half=g&1.
    __shared__ float sq[3 * PERN];       // 12 KB
    __shared__ int   slotbuf[16][64];    // 4 KB

    const int b   = blockIdx.x >> 4;     // 16 blocks per batch
    const int tid = threadIdx.x;
    const int w   = tid >> 6;
    const int l   = tid & 63;
    const int i   = __builtin_amdgcn_readfirstlane((blockIdx.x & 15) * 16 + w);

    {
        const float* gp = pos + (size_t)b * PERN * 3;
        const int fo = (((tid >> 7) << 6) | (tid & 63)) * 2 + ((tid >> 6) & 1);
        sq[fo]            = gp[tid * 3 + 0];
        sq[PERN + fo]     = gp[tid * 3 + 1];
        sq[2 * PERN + fo] = gp[tid * 3 + 2];
    }
    __syncthreads();

    const int fi = (((i >> 7) << 6) | (i & 63)) * 2 + ((i >> 6) & 1);
    const float xi = sq[fi], yi = sq[PERN + fi], zi = sq[2 * PERN + fi];
    // (q - xi)^2 == (xi - q)^2 bitwise; pre-negate so the scan is pure pk ops.
    const v2f nx = {-xi, -xi}, ny = {-yi, -yi}, nz = {-zi, -zi};

    const v2f* xq = (const v2f*)sq;
    const v2f* yq = (const v2f*)(sq + PERN);
    const v2f* zq = (const v2f*)(sq + 2 * PERN);

    // ---- phase A: all 8 pair-group d2 vectors, 2-deep load pipeline ----
    v2f d2v[8];
    {
        v2f cx = xq[l], cy = yq[l], cz = zq[l];
#pragma unroll
        for (int p = 0; p < 8; ++p) {
            v2f tx = cx, ty = cy, tz = cz;
            if (p < 7) {  // prefetch next group's coords during this group's math
                tx = xq[(p + 1) * 64 + l];
                ty = yq[(p + 1) * 64 + l];
                tz = zq[(p + 1) * 64 + l];
            }
            const v2f dx = pk_add(cx, nx), dy = pk_add(cy, ny), dz = pk_add(cz, nz);
            // exact reference order per half: (dx^2 + dy^2) + dz^2
            d2v[p] = pk_add(pk_add(pk_mul(dx, dx), pk_mul(dy, dy)), pk_mul(dz, dz));
            cx = tx; cy = ty; cz = tz;
        }
    }

    // ---- phase B: per-lane valids + batched ballots (masks in SGPRs) ----
    const int  gi       = i >> 6;          // scalar: which ii group holds self
    const bool not_self = (l != (i & 63)); // lane-level self test
    bool va[16];
    unsigned long long msk[16];
#pragma unroll
    for (int g = 0; g < 16; ++g) {
        const int p = g >> 1;
        const float d2 = (g & 1) ? d2v[p].y : d2v[p].x;
        bool v = d2 < 36.0f;
        if (g < 4 && g == gi) v = v && not_self;  // ii self-exclusion
        va[g]  = v;
        msk[g] = __ballot(v);
    }

    int* slots = slotbuf[w];

    // ---- ii compaction: groups 0..3 (branch-free main, break in pad) ----
    int S0ii;
    {
        int cnt = 0;
#pragma unroll
        for (int g = 0; g < 4; ++g) {
            const int slot = cnt + prefix_lt(msk[g]);
            if (va[g] && slot < KK) slots[slot] = g * 64 + l;
            cnt += __popcll(msk[g]);
        }
        S0ii = cnt < KK ? cnt : KK;
        if (S0ii < KK) {  // pad: smallest invalid indices (incl. j==i)
            int pc = S0ii;
#pragma unroll
            for (int g = 0; g < 4; ++g) {
                const unsigned long long inv = ~msk[g];
                const int slot = pc + prefix_lt(inv);
                if (!va[g] && slot < KK) slots[slot] = g * 64 + l;
                pc += __popcll(inv);
                if (pc >= KK) break;  // invalid bits dense: exits after ~1 group
            }
        }
    }

    // ---- io compaction: groups 4..15 (candidates 256..1023) ----
    int S0io;
    {
        int cnt = 0;
#pragma unroll
        for (int g = 4; g < 16; ++g) {
            const int slot = cnt + prefix_lt(msk[g]);
            if (va[g] && slot < KK) slots[KK + slot] = g * 64 + l;
            cnt += __popcll(msk[g]);
        }
        S0io = cnt < KK ? cnt : KK;
        if (S0io < KK) {
            int pc = S0io;
#pragma unroll
            for (int g = 4; g < 16; ++g) {
                const unsigned long long inv = ~msk[g];
                const int slot = pc + prefix_lt(inv);
                if (!va[g] && slot < KK) slots[KK + slot] = g * 64 + l;
                pc += __popcll(inv);
                if (pc >= KK) break;
            }
        }
    }

    // ---- epilogue: half-wave pull, 4 coalesced wave-wide stores ----
    {
        const int h = l >> 5;        // 0 = ii row, 1 = io row
        const int k = l & 31;
        const int idx = slots[l];    // candidate index within batch [0,1024)
        const int fg = (((idx >> 7) << 6) | (idx & 63)) * 2 + ((idx >> 6) & 1);
        const float dxe = xi - sq[fg];
        const float dye = yi - sq[PERN + fg];
        const float dze = zi - sq[2 * PERN + fg];
        const float d2e = dxe * dxe + dye * dye + dze * dze;  // dist tol ~0.12: any order

        const int S0 = h ? S0io : S0ii;
        const bool mv = k < S0;
        const float dist = mv ? __builtin_amdgcn_sqrtf(d2e) : 0.0f;

        const int goff = b * PERN;
        const unsigned e0  = (unsigned)(b * 256 + i) * KK;
        const unsigned off = (h ? 4u * EE : 0u) + e0 + (unsigned)k;

        out[off]           = (float)(goff + idx);  // src (io idx already incl. +NIN)
        out[off + EE]      = (float)(goff + i);    // tgt
        out[off + 2u * EE] = mv ? 1.0f : 0.0f;     // mask
        out[off + 3u * EE] = dist;                 // dist
    }
}

extern "C" void kernel_launch(void* const* d_in, const int* in_sizes, int n_in,
                              void* d_out, int out_size, void* d_ws, size_t ws_size,
                              hipStream_t stream) {
    const float* pos = (const float*)d_in[0];
    float* out = (float*)d_out;

    // 16 blocks/batch x 256 batches; 1024 threads = 16 waves = 16 targets/block.
    mo3e_kernel<<<dim3(BB * 16), dim3(1024), 0, stream>>>(pos, out);
}

// Round 8
// 101.975 us; speedup vs baseline: 1.0310x; 1.0031x over previous
//
#include <hip/hip_runtime.h>

// Mo3ENet neighbor selection: B=256, PER=1024, NIN=256, NOUT=768, K=32, R=6
// Round 8: branchless ballot compaction (cndmask->dump, min-clamp spill),
// flat LDS with (c, c+64) candidate pairing, 256-thread blocks.
// Outputs (concatenated float32):
//   [0) src_ii | [E) tgt | [2E) m_ii | [3E) dist_ii |
//   [4E) src_io | [5E) tgt | [6E) m_io | [7E) dist_io
//
// Per-wave LDS slot row (128 ints): [0..31] ii slots | [32..63] io slots |
// [64..127] dead (dump + spill). ii main/pad may spill into 32..63 — always
// overwritten later by io main+pad (program order within the same wave).

constexpr int KK = 32;
constexpr unsigned EE = 2097152u;  // elements per output array

typedef float v2f __attribute__((ext_vector_type(2)));

__device__ __forceinline__ v2f pk_add(v2f a, v2f b) {
    v2f d; asm("v_pk_add_f32 %0, %1, %2" : "=v"(d) : "v"(a), "v"(b)); return d;
}
__device__ __forceinline__ v2f pk_mul(v2f a, v2f b) {
    v2f d; asm("v_pk_mul_f32 %0, %1, %2" : "=v"(d) : "v"(a), "v"(b)); return d;
}

__device__ __forceinline__ int prefix_lt(unsigned long long m) {
    return __builtin_amdgcn_mbcnt_hi((unsigned)(m >> 32),
           __builtin_amdgcn_mbcnt_lo((unsigned)m, 0u));
}

__global__ __launch_bounds__(256) void mo3e_kernel(const float* __restrict__ pos,
                                                   float* __restrict__ out) {
    __shared__ float sq[3072];          // flat xyz, 12 KB
    __shared__ int   slotrow[4][128];   // 2 KB, one row per wave

    const int blk = blockIdx.x;
    const int b   = blk >> 6;           // 64 blocks per batch
    const int tid = threadIdx.x;
    const int w   = tid >> 6;
    const int l   = tid & 63;
    const int i   = __builtin_amdgcn_readfirstlane(((blk & 63) << 2) | w);

    // Stage batch positions: 3 coalesced float4 per thread.
    {
        const float4* g4 = (const float4*)(pos + (size_t)b * 3072);
        float4* s4 = (float4*)sq;
        s4[tid      ] = g4[tid      ];
        s4[tid + 256] = g4[tid + 256];
        s4[tid + 512] = g4[tid + 512];
    }
    __syncthreads();

    const float xi = sq[3 * i], yi = sq[3 * i + 1], zi = sq[3 * i + 2];
    // (q + (-t)) == (q - t); (q-t)^2 == (t-q)^2 bitwise. Per-half op order
    // (dx^2 + dy^2) + dz^2 matches the reference exactly; asm pk ops cannot
    // be contracted. Predicate d2 < 36.0f is bit-identical to sqrt(d2) < 6.
    const v2f nx = {-xi, -xi}, ny = {-yi, -yi}, nz = {-zi, -zi};

    int* __restrict__ row = slotrow[w];
    const int dump = 64 + l;            // per-lane dead entry (conflict-free)

    unsigned long long msk[16];
    int cii = 0, cio = 0;
    int av = 3 * l;                     // dword index of cand (c0 + l) x-coord

    // ================= ii scan: iters 0..1, candidates [0,256) =================
#pragma unroll
    for (int it = 0; it < 2; ++it) {
        const float xa = sq[av], ya = sq[av + 1], za = sq[av + 2];
        const float xb = sq[av + 192], yb = sq[av + 193], zb = sq[av + 194];
        av += 384;
        const v2f qx = {xa, xb}, qy = {ya, yb}, qz = {za, zb};
        const v2f dx = pk_add(qx, nx), dy = pk_add(qy, ny), dz = pk_add(qz, nz);
        const v2f d2 = pk_add(pk_add(pk_mul(dx, dx), pk_mul(dy, dy)), pk_mul(dz, dz));
        const int c0 = it * 128;
        {   // group 2*it: candidates [c0, c0+64)
            const bool va = (d2.x < 36.0f) & ((c0 + l) != i);
            const unsigned long long m = __ballot(va);
            msk[2 * it] = m;
            int ent = cii + prefix_lt(m);
            ent = ent < 127 ? ent : 127;          // spill -> dead/overwritten
            ent = va ? ent : dump;
            row[ent] = c0 + l;
            cii += __popcll(m);
        }
        {   // group 2*it+1: candidates [c0+64, c0+128)
            const bool vb = (d2.y < 36.0f) & ((c0 + 64 + l) != i);
            const unsigned long long m = __ballot(vb);
            msk[2 * it + 1] = m;
            int ent = cii + prefix_lt(m);
            ent = ent < 127 ? ent : 127;
            ent = vb ? ent : dump;
            row[ent] = c0 + 64 + l;
            cii += __popcll(m);
        }
    }
    const int S0ii = cii < KK ? cii : KK;
    if (cii < KK) {  // ii pad: smallest invalid indices (incl. j==i)
        int pc = cii;
#pragma unroll
        for (int g = 0; g < 4; ++g) {
            const unsigned long long inv = ~msk[g];
            const bool pm = (inv >> l) & 1ull;
            int ent = pc + prefix_lt(inv);        // max 31+63=94: dead/overwritten
            ent = pm ? ent : dump;
            row[ent] = g * 64 + l;
            pc += __popcll(inv);
            if (pc >= KK) break;                  // inv dense: ~1 iteration
        }
    }

    // ================= io scan: iters 2..7, candidates [256,1024) =================
#pragma unroll
    for (int it = 2; it < 8; ++it) {
        const float xa = sq[av], ya = sq[av + 1], za = sq[av + 2];
        const float xb = sq[av + 192], yb = sq[av + 193], zb = sq[av + 194];
        av += 384;
        const v2f qx = {xa, xb}, qy = {ya, yb}, qz = {za, zb};
        const v2f dx = pk_add(qx, nx), dy = pk_add(qy, ny), dz = pk_add(qz, nz);
        const v2f d2 = pk_add(pk_add(pk_mul(dx, dx), pk_mul(dy, dy)), pk_mul(dz, dz));
        const int c0 = it * 128;
        {
            const bool va = (d2.x < 36.0f);
            const unsigned long long m = __ballot(va);
            msk[2 * it] = m;
            int ent = cio + prefix_lt(m);
            ent = ent < 95 ? ent : 95;            // +32 => max 127 (dead)
            ent = va ? ent + KK : dump;
            row[ent] = c0 + l;
            cio += __popcll(m);
        }
        {
            const bool vb = (d2.y < 36.0f);
            const unsigned long long m = __ballot(vb);
            msk[2 * it + 1] = m;
            int ent = cio + prefix_lt(m);
            ent = ent < 95 ? ent : 95;
            ent = vb ? ent + KK : dump;
            row[ent] = c0 + 64 + l;
            cio += __popcll(m);
        }
    }
    const int S0io = cio < KK ? cio : KK;
    if (cio < KK) {  // io pad
        int pc = cio;
#pragma unroll
        for (int g = 4; g < 16; ++g) {
            const unsigned long long inv = ~msk[g];
            const bool pm = (inv >> l) & 1ull;
            int ent = pc + prefix_lt(inv);        // +32 => max 126 (dead)
            ent = pm ? ent + KK : dump;
            row[ent] = g * 64 + l;
            pc += __popcll(inv);
            if (pc >= KK) break;
        }
    }

    // ===== epilogue: lane l reads entry l (0..31 ii, 32..63 io), 4 coalesced stores =====
    {
        const int idx = row[l];                   // same-wave RAW: no barrier needed
        const float qx = sq[3 * idx], qy = sq[3 * idx + 1], qz = sq[3 * idx + 2];
        const float ddx = xi - qx, ddy = yi - qy, ddz = zi - qz;
        const float d2e = ddx * ddx + ddy * ddy + ddz * ddz;  // dist tol ~0.03: any order

        const bool isA = l < KK;
        const int  S0  = isA ? S0ii : S0io;
        const bool mv  = (l & 31) < S0;
        const float dist = mv ? __builtin_amdgcn_sqrtf(d2e) : 0.0f;

        const int goff = b * 1024;
        const unsigned e0  = (unsigned)(b * 256 + i) * 32u;
        const unsigned off = (isA ? 0u : 4u * EE - 32u) + e0 + (unsigned)l;

        out[off]           = (float)(goff + idx);  // src (io idx already >= 256)
        out[off + EE]      = (float)(goff + i);    // tgt
        out[off + 2u * EE] = mv ? 1.0f : 0.0f;     // mask
        out[off + 3u * EE] = dist;                 // dist
    }
}

extern "C" void kernel_launch(void* const* d_in, const int* in_sizes, int n_in,
                              void* d_out, int out_size, void* d_ws, size_t ws_size,
                              hipStream_t stream) {
    const float* pos = (const float*)d_in[0];
    float* out = (float*)d_out;

    // 64 blocks/batch x 256 batches; 256 threads = 4 waves = 4 targets/block.
    mo3e_kernel<<<dim3(256 * 64), dim3(256), 0, stream>>>(pos, out);
}